// Round 4
// baseline (398.608 us; speedup 1.0000x reference)
//
#include <hip/hip_runtime.h>

// GQA_22436909154699: softmax over a size-1 axis == 1.0, so the reference
// reduces to  out[bl, g*512+h*64+d] = (x @ Wkv + bkv)[bl, g*128+64+d].
// => one (16384 x 2048) @ (2048 x 256) GEMM (v-cols only) + broadcast x8.
// R11: ZERO-SYNC main loop. Evidence: R7(31% occ) and R10(59% occ) both
// pinned at 2.1 TB/s with all pipes <6% busy -> barrier/drain convoys are
// the bottleneck, not occupancy and not HBM. The MFMA A-fragment is 8
// CONTIGUOUS k-elems of one row (32 B of x), so each lane loads its own
// fragment straight from global (2x dwordx4) and converts f32->f16 in-lane;
// B fragments load directly from L2-resident Bt. No LDS, no barriers, no
// lgkmcnt drains in the K-loop. Wave = independent 16m x 64n tile, depth-2
// register ping-pong over 32-wide k half-slabs (~84 VGPR, no spill at
// (256,4)). LDS + one __syncthreads only in the bias+broadcast epilogue.

#define EMBED 2048
#define SV 272  // epilogue LDS row stride in floats (272*4B: +16 bank skew)

typedef _Float16 half8 __attribute__((ext_vector_type(8)));
typedef _Float16 half4v __attribute__((ext_vector_type(4)));
typedef float f32x4 __attribute__((ext_vector_type(4)));

// ---- pre-pass: Bt[n][k] (f16) = Wkv[k][vcol(n)], vcol(n)=(n>>6)*128+64+(n&63)
__global__ __launch_bounds__(256) void prep_b(const float* __restrict__ Wkv,
                                              _Float16* __restrict__ Bt) {
  const int t = threadIdx.x;
  const int kb = blockIdx.x * 4;  // 512 blocks cover k = 0..2047
  const int vcol = ((t >> 6) * 128) + 64 + (t & 63);
  float v[4];
#pragma unroll
  for (int i = 0; i < 4; ++i) v[i] = Wkv[(size_t)(kb + i) * 512 + vcol];
  half4v h;
#pragma unroll
  for (int i = 0; i < 4; ++i) h[i] = (_Float16)v[i];
  *(half4v*)&Bt[(size_t)t * EMBED + kb] = h;
}

// ---- main: block = 16 rows, 4 waves = 4 n-tiles of 64. 1024 blocks.
__global__ __launch_bounds__(256, 4) void gqa_main(
    const float* __restrict__ x, const _Float16* __restrict__ Bt,
    const float* __restrict__ bkv, float* __restrict__ out) {
  __shared__ __align__(16) float Vs[16][SV];  // 17408 B, epilogue only

  const int tid = threadIdx.x;
  const int w = tid >> 6;    // wave = n-tile index 0..3 (cols w*64..+64)
  const int lane = tid & 63;
  const int lm = lane & 15;  // A row / B row / C col within 16
  const int lq = lane >> 4;  // k-subchunk (8 halfs) / C row quad
  const int row0 = blockIdx.x * 16;

  // A fragment source: lane (lm,lq) reads x[row0+lm][k0 + lq*8 .. +8] (f32)
  const float* apx = x + (size_t)(row0 + lm) * EMBED + lq * 8;
  // B fragment source: lane (lm,lq) reads Bt[w*64 + ni*16 + lm][k0 + lq*8..]
  const _Float16* bp0 = Bt + (size_t)(w * 64 + lm) * EMBED + lq * 8;

  // depth-2 named prefetch sets: one 32-wide k half-slab each
  f32x4 a0_0, a1_0, a0_1, a1_1;
  half8 b_0[4], b_1[4];  // indexed only by compile-time constants

#define LOADX(h, A0, A1, B)                          \
  {                                                  \
    const float* p_ = apx + (h) * 32;                \
    A0 = *(const f32x4*)p_;                          \
    A1 = *(const f32x4*)(p_ + 4);                    \
    const _Float16* q_ = bp0 + (h) * 32;             \
    B[0] = *(const half8*)q_;                        \
    B[1] = *(const half8*)(q_ + 16 * EMBED);         \
    B[2] = *(const half8*)(q_ + 32 * EMBED);         \
    B[3] = *(const half8*)(q_ + 48 * EMBED);         \
  }
#define CONS(A0, A1, B)                                                  \
  {                                                                      \
    half8 af_;                                                           \
    _Pragma("unroll") for (int j_ = 0; j_ < 4; ++j_)                     \
        af_[j_] = (_Float16)A0[j_];                                      \
    _Pragma("unroll") for (int j_ = 0; j_ < 4; ++j_)                     \
        af_[4 + j_] = (_Float16)A1[j_];                                  \
    _Pragma("unroll") for (int n_ = 0; n_ < 4; ++n_)                     \
        acc[n_] = __builtin_amdgcn_mfma_f32_16x16x32_f16(af_, B[n_],     \
                                                         acc[n_], 0, 0, 0); \
  }

  f32x4 acc[4] = {};  // 16m x 64n: acc[ni], col = ni*16+lm, row = lq*4+r

  LOADX(0, a0_0, a1_0, b_0);
  LOADX(1, a0_1, a1_1, b_1);

  // 64 half-slabs of k=32; refill AFTER consume -> prefetch distance ~1 iter
  for (int h = 0; h < 64; h += 2) {
    CONS(a0_0, a1_0, b_0);
    if (h + 2 < 64) LOADX(h + 2, a0_0, a1_0, b_0);
    CONS(a0_1, a1_1, b_1);
    if (h + 3 < 64) LOADX(h + 3, a0_1, a1_1, b_1);
  }

  // epilogue: bias, stash 16x256 V-tile in LDS, then broadcast x8 coalesced
#pragma unroll
  for (int ni = 0; ni < 4; ++ni) {
    const int n = w * 64 + ni * 16 + lm;      // 0..255
    const float bias = bkv[w * 128 + 64 + ni * 16 + lm];
    f32x4 v = acc[ni];
#pragma unroll
    for (int r = 0; r < 4; ++r) {
      Vs[lq * 4 + r][n] = v[r] + bias;
    }
  }
  __syncthreads();

  // block writes out[row0 .. row0+16][0 .. 2048], fully coalesced
  f32x4* out4 = (f32x4*)(out + (size_t)row0 * EMBED);
#pragma unroll 8
  for (int i = 0; i < 32; ++i) {
    const int f = i * 256 + tid;  // 0..8191 over 16 rows x 512 float4
    const int row = f >> 9;
    const int c4 = f & 511;       // float4 col in out row
    const int grp = c4 >> 7;      // group g = n>>6
    const int d4 = c4 & 15;       // d float4 within head
    out4[(size_t)row * 512 + c4] = *(const f32x4*)&Vs[row][grp * 64 + d4 * 4];
  }
}

extern "C" void kernel_launch(void* const* d_in, const int* in_sizes, int n_in,
                              void* d_out, int out_size, void* d_ws, size_t ws_size,
                              hipStream_t stream) {
  const float* x = (const float*)d_in[0];
  // d_in[1] = Wq, d_in[2] = bq : dead code (softmax over size-1 axis == 1)
  const float* Wkv = (const float*)d_in[3];
  const float* bkv = (const float*)d_in[4];
  float* out = (float*)d_out;
  _Float16* Bt = (_Float16*)d_ws;  // 256*2048 f16 = 1 MB scratch

  prep_b<<<512, 256, 0, stream>>>(Wkv, Bt);
  gqa_main<<<1024, 256, 0, stream>>>(x, Bt, bkv, out);
}

// Round 5
// 265.853 us; speedup vs baseline: 1.4994x; 1.4994x over previous
//
#include <hip/hip_runtime.h>

// GQA_22436909154699: softmax over a size-1 axis == 1.0, so the reference
// reduces to  out[bl, g*512+h*64+d] = (x @ Wkv + bkv)[bl, g*128+64+d].
// => one (16384 x 2048) @ (2048 x 256) GEMM (v-cols only) + broadcast x8.
// R12: T3+T4 port. Evidence: R7/R10 (LDS staging, drain barriers) and R11
// (per-lane direct frags) all stall ~1000s of cycles per K-slab — the
// 2-phase stage+wait+barrier critical path. Fix per m218/m201: stage via
// global_load_lds DMA (no reg round-trip, no ds_write), depth-4 LDS ring,
// counted s_waitcnt vmcnt(12) (never drains in-loop), 1 barrier/slab.
// Block = 64 rows x ALL 256 cols (x read exactly once, 1 block/CU, 256
// blocks, no tail). Bank conflicts on LDS reads killed by both-sides XOR
// swizzle (pre-swizzled per-lane global src + swizzled ds_read, rule #21):
// A: s(row)=(row&7)<<4 ; B: s(n)=((n>>1)&3)<<4 (+natural 64*(n&1) bit).

#define EMBED 2048
#define SV 272  // epilogue LDS row stride in floats

typedef _Float16 half8 __attribute__((ext_vector_type(8)));
typedef _Float16 half4v __attribute__((ext_vector_type(4)));
typedef float f32x4 __attribute__((ext_vector_type(4)));

#define GLOAD16(g, l)                                                      \
  __builtin_amdgcn_global_load_lds(                                        \
      (const __attribute__((address_space(1))) void*)(g),                  \
      (__attribute__((address_space(3))) void*)(l), 16, 0, 0)

// ---- pre-pass: Bt[n][k] (f16) = Wkv[k][vcol(n)], vcol(n)=(n>>6)*128+64+(n&63)
__global__ __launch_bounds__(256) void prep_b(const float* __restrict__ Wkv,
                                              _Float16* __restrict__ Bt) {
  const int t = threadIdx.x;
  const int kb = blockIdx.x * 4;  // 512 blocks cover k = 0..2047
  const int vcol = ((t >> 6) * 128) + 64 + (t & 63);
  float v[4];
#pragma unroll
  for (int i = 0; i < 4; ++i) v[i] = Wkv[(size_t)(kb + i) * 512 + vcol];
  half4v h;
#pragma unroll
  for (int i = 0; i < 4; ++i) h[i] = (_Float16)v[i];
  *(half4v*)&Bt[(size_t)t * EMBED + kb] = h;
}

// ---- main: 256 blocks, block = 64 rows x 256 cols, 4 waves (64 n-cols each)
__global__ __launch_bounds__(256) void gqa_main(
    const float* __restrict__ x, const _Float16* __restrict__ Bt,
    const float* __restrict__ bkv, float* __restrict__ out) {
  // ring: 4 x (A slab 64rows x 128B f32 = 8KB) + 4 x (B slab 256rows x 64B f16
  // = 16KB) = 96 KB -> hard 1 block/CU.
  __shared__ __align__(16) char smem[4 * 8192 + 4 * 16384];
  char* const Ab = smem;
  char* const Bb = smem + 4 * 8192;
  float* const Vs = (float*)smem;  // epilogue overlay [8][SV] = 8.7 KB

  const int tid = threadIdx.x;
  const int w = tid >> 6;    // wave: n-cols [w*64, w*64+64)
  const int lane = tid & 63;
  const int lm = lane & 15;
  const int lq = lane >> 4;
  const int row0 = blockIdx.x * 64;

  // ---- staging sources (per-lane, pre-swizzled cols); dest = base + lane*16
  // A instr i: row = w*16 + i*8 + (lane>>3); dest col (lane&7)*16;
  //            src col = dest ^ ((row&7)<<4), row&7 = lane>>3.
  const int acol = ((lane & 7) ^ (lane >> 3)) << 4;
  const char* asrc0 = (const char*)x +
      (size_t)(row0 + w * 16 + (lane >> 3)) * (EMBED * 4) + acol;
  const char* asrc1 = asrc0 + (size_t)8 * EMBED * 4;
  const int adst0 = (w * 16) * 128;        // + i*1024
  // B instr j: n = w*64 + j*16 + (lane>>2); dest col (lane&3)*16;
  //            src col = dest ^ (((n>>1)&3)<<4), (n>>1)&3 = (lane>>3)&3.
  const int bcol = (((lane & 3) << 4) ^ (((lane >> 3) & 3) << 4));
  const char* bsrc0 = (const char*)Bt +
      (size_t)(w * 64 + (lane >> 2)) * (EMBED * 2) + bcol;
  const int bdst0 = (w * 64) * 64;         // + j*1024

#define STAGE(b, s)                                                        \
  {                                                                        \
    const size_t sa_ = (size_t)(s) * 128; /* A k-bytes per slab */         \
    GLOAD16(asrc0 + sa_, Ab + (b) * 8192 + adst0);                         \
    GLOAD16(asrc1 + sa_, Ab + (b) * 8192 + adst0 + 1024);                  \
    const size_t sb_ = (size_t)(s) * 64;  /* B k-bytes per slab */         \
    GLOAD16(bsrc0 + sb_, Bb + (b) * 16384 + bdst0);                        \
    GLOAD16(bsrc0 + sb_ + (size_t)16 * EMBED * 2,                          \
            Bb + (b) * 16384 + bdst0 + 1024);                              \
    GLOAD16(bsrc0 + sb_ + (size_t)32 * EMBED * 2,                          \
            Bb + (b) * 16384 + bdst0 + 2048);                              \
    GLOAD16(bsrc0 + sb_ + (size_t)48 * EMBED * 2,                          \
            Bb + (b) * 16384 + bdst0 + 3072);                              \
  }

  // read swizzles (lane-const)
  const int arswz = (lm & 7) << 4;
  const int brswz = ((lm >> 1) & 3) << 4;

#define COMPUTE(b)                                                         \
  {                                                                        \
    const char* Ar_ = Ab + (b) * 8192 + lm * 128;                          \
    const char* Br_ = Bb + (b) * 16384 + (w * 64 + lm) * 64 +              \
                      ((lq << 4) ^ brswz);                                 \
    half8 bf_[4];                                                          \
    _Pragma("unroll") for (int ni = 0; ni < 4; ++ni)                       \
        bf_[ni] = *(const half8*)(Br_ + ni * 1024);                        \
    _Pragma("unroll") for (int mi = 0; mi < 4; ++mi) {                     \
      f32x4 a0_ = *(const f32x4*)(Ar_ + mi * 2048 + ((lq << 5) ^ arswz));  \
      f32x4 a1_ = *(const f32x4*)(Ar_ + mi * 2048 + (((lq << 5) + 16) ^ arswz)); \
      half8 af_;                                                           \
      _Pragma("unroll") for (int j = 0; j < 4; ++j) af_[j] = (_Float16)a0_[j]; \
      _Pragma("unroll") for (int j = 0; j < 4; ++j) af_[4 + j] = (_Float16)a1_[j]; \
      _Pragma("unroll") for (int ni = 0; ni < 4; ++ni)                     \
          acc[mi][ni] = __builtin_amdgcn_mfma_f32_16x16x32_f16(            \
              af_, bf_[ni], acc[mi][ni], 0, 0, 0);                         \
    }                                                                      \
  }

  f32x4 acc[4][4] = {};

  // prologue: stage slabs 0..2 (18 loads in flight)
  STAGE(0, 0);
  STAGE(1, 1);
  STAGE(2, 2);

  // steady state: wait slab t (vmcnt 18->12), barrier, stage t+3 (safe:
  // buf[(t+3)&3]'s old tenant slab t-1 was consumed before this barrier),
  // compute t. Tail: junk re-stages of slab 63 keep vmcnt counts uniform.
  for (int tt = 0; tt < 64; tt += 4) {
#define ITER(T, BC, BS)                                                    \
    asm volatile("s_waitcnt vmcnt(12)" ::: "memory");                      \
    __builtin_amdgcn_s_barrier();                                          \
    {                                                                      \
      const int ss_ = (T) + 3 < 64 ? (T) + 3 : 63;                         \
      STAGE(BS, ss_);                                                      \
    }                                                                      \
    COMPUTE(BC);
    ITER(tt + 0, 0, 3)
    ITER(tt + 1, 1, 0)
    ITER(tt + 2, 2, 1)
    ITER(tt + 3, 3, 2)
#undef ITER
  }

  // epilogue: drain junk DMAs before overlaying smem with Vs
  asm volatile("s_waitcnt vmcnt(0)" ::: "memory");
  __syncthreads();

  float bias[4];
#pragma unroll
  for (int ni = 0; ni < 4; ++ni) bias[ni] = bkv[w * 128 + 64 + ni * 16 + lm];

  // 8 chunks of 8 rows: acc -> Vs (v-cols 0..255) -> broadcast x8 coalesced
#pragma unroll
  for (int c = 0; c < 8; ++c) {
    const int mi = c >> 1;  // compile-time after unroll
    if ((lq >> 1) == (c & 1)) {
#pragma unroll
      for (int ni = 0; ni < 4; ++ni) {
        const int n = w * 64 + ni * 16 + lm;
        f32x4 v = acc[mi][ni];
#pragma unroll
        for (int r = 0; r < 4; ++r)
          Vs[((lq & 1) * 4 + r) * SV + n] = v[r] + bias[ni];
      }
    }
    __syncthreads();
    f32x4* out4 = (f32x4*)(out + (size_t)(row0 + c * 8) * EMBED);
#pragma unroll 4
    for (int i = 0; i < 16; ++i) {
      const int f = i * 256 + tid;  // 8 rows x 512 float4
      const int row = f >> 9;
      const int c4 = f & 511;
      const int grp = c4 >> 7;
      const int d4 = c4 & 15;
      out4[(size_t)row * 512 + c4] =
          *(const f32x4*)&Vs[row * SV + grp * 64 + d4 * 4];
    }
    __syncthreads();
  }
}

extern "C" void kernel_launch(void* const* d_in, const int* in_sizes, int n_in,
                              void* d_out, int out_size, void* d_ws, size_t ws_size,
                              hipStream_t stream) {
  const float* x = (const float*)d_in[0];
  // d_in[1] = Wq, d_in[2] = bq : dead code (softmax over size-1 axis == 1)
  const float* Wkv = (const float*)d_in[3];
  const float* bkv = (const float*)d_in[4];
  float* out = (float*)d_out;
  _Float16* Bt = (_Float16*)d_ws;  // 256*2048 f16 = 1 MB scratch

  prep_b<<<512, 256, 0, stream>>>(Wkv, Bt);
  gqa_main<<<256, 256, 0, stream>>>(x, Bt, bkv, out);
}